// Round 2
// baseline (809.033 us; speedup 1.0000x reference)
//
#include <hip/hip_runtime.h>
#include <math.h>

#define N   4096
#define NO  4097   // output spatial dim (4096 + 4pad - 4 + 1)
#define TO  32     // output tile

struct OrientCoef { float c[8]; float s[8]; };

// LDS ~49 KB -> 3 blocks/CU (LDS-bound), 12 waves/CU.
__global__ __launch_bounds__(256) void sift_fused(const float* __restrict__ x,
                                                  float* __restrict__ out,
                                                  OrientCoef cf) {
    const int i0  = blockIdx.y * TO;
    const int j0  = blockIdx.x * TO;
    const int tid = threadIdx.x;

    __shared__ float         xs[37][38];
    __shared__ float         smag[35][36];
    __shared__ unsigned char sidx[35][36];
    __shared__ float         hsum[8][35][33];

    // ---- stage x halo (zero-padded) + zero hsum ----
    for (int l = tid; l < 37 * 37; l += 256) {
        int lr = l / 37, lc = l % 37;
        int gr = i0 - 3 + lr, gc = j0 - 3 + lc;
        float v = 0.0f;
        if (gr >= 0 && gr < N && gc >= 0 && gc < N) v = x[(size_t)gr * N + gc];
        xs[lr][lc] = v;
    }
    float* hflat = &hsum[0][0][0];
    for (int l = tid; l < 8 * 35 * 33; l += 256) hflat[l] = 0.0f;
    __syncthreads();

    // ---- Sobel (cross-correlation, zero pad) + magnitude + orientation argmax ----
    for (int l = tid; l < 35 * 35; l += 256) {
        int lr = l / 35, lc = l % 35;
        int gr = i0 - 2 + lr, gc = j0 - 2 + lc;
        float mag = 0.0f;
        int best = 0;
        if (gr >= 0 && gr < N && gc >= 0 && gc < N) {
            float x00 = xs[lr][lc],     x01 = xs[lr][lc + 1],     x02 = xs[lr][lc + 2];
            float x10 = xs[lr + 1][lc],                           x12 = xs[lr + 1][lc + 2];
            float x20 = xs[lr + 2][lc], x21 = xs[lr + 2][lc + 1], x22 = xs[lr + 2][lc + 2];
            // unflipped sobel taps (lax conv = cross-correlation)
            float dx = (x02 - x00) + 2.0f * (x12 - x10) + (x22 - x20);
            float dy = (x20 - x00) + 2.0f * (x21 - x01) + (x22 - x02);
            mag = sqrtf(dx * dx + dy * dy);
            // per-bin coefficients (reference rounds each f32 angle separately
            // before cos/sin -- the W matrix is NOT ulp-symmetric)
            float bv = fmaf(cf.s[0], dy, cf.c[0] * dx);
            #pragma unroll
            for (int o = 1; o < 8; ++o) {
                float cs = fmaf(cf.s[o], dy, cf.c[o] * dx);
                if (cs > bv) { bv = cs; best = o; }
            }
        }
        smag[lr][lc] = mag;
        sidx[lr][lc] = (unsigned char)best;
    }
    __syncthreads();

    // ---- horizontal 4-window scatter into per-channel sums ----
    for (int p = tid; p < 35 * 32; p += 256) {
        int r = p / 32, jt = p % 32;
        #pragma unroll
        for (int w = 0; w < 4; ++w) {
            float m  = smag[r][jt + w];
            int   ii = sidx[r][jt + w];
            hsum[ii][r][jt] += m;   // unique (r,jt) per thread -> race-free
        }
    }
    __syncthreads();

    // ---- vertical 4-row sum + store ----
    #pragma unroll
    for (int k = 0; k < 32; ++k) {
        int p  = k * 256 + tid;
        int jt = p & 31;
        int it = (p >> 5) & 31;
        int o  = p >> 10;
        int i = i0 + it, j = j0 + jt;
        if (i < NO && j < NO) {
            float s = hsum[o][it][jt] + hsum[o][it + 1][jt] +
                      hsum[o][it + 2][jt] + hsum[o][it + 3][jt];
            out[((size_t)o * NO + i) * NO + j] = s;
        }
    }
}

extern "C" void kernel_launch(void* const* d_in, const int* in_sizes, int n_in,
                              void* d_out, int out_size, void* d_ws, size_t ws_size,
                              hipStream_t stream) {
    const float* x = (const float*)d_in[0];
    float* out = (float*)d_out;

    // Emulate reference coefficient pipeline exactly:
    //   angle_o = f32( f32(2o+1) * f32(pi/8) ); coeff = f32(cos/sin(angle_o))
    OrientCoef cf;
    const float pi8 = (float)(M_PI / 8.0);   // fp32(pi/8)
    for (int o = 0; o < 8; ++o) {
        float angle = (float)(2 * o + 1) * pi8;          // f32 multiply
        cf.c[o] = (float)cos((double)angle);             // correctly-rounded f32
        cf.s[o] = (float)sin((double)angle);
    }

    dim3 grid((NO + TO - 1) / TO, (NO + TO - 1) / TO);   // 129 x 129
    sift_fused<<<grid, dim3(256), 0, stream>>>(x, out, cf);
}